// Round 6
// baseline (535.365 us; speedup 1.0000x reference)
//
#include <hip/hip_runtime.h>
#include <cstddef>

typedef __attribute__((ext_vector_type(4))) float  float4v;
typedef __attribute__((ext_vector_type(8))) short  short8v;
typedef __attribute__((ext_vector_type(8))) unsigned short ushort8v;
typedef __attribute__((ext_vector_type(8))) __bf16 bf16x8;
typedef __attribute__((ext_vector_type(4))) float  f32x4;

static constexpr int C_DIM = 768;
static constexpr int O_DIM = 768;
static constexpr int NEL   = 49152;  // 768*64

__device__ __forceinline__ unsigned short f2bf(float f) {
  __bf16 h = (__bf16)f;
  return __builtin_bit_cast(unsigned short, h);
}

// forward 8-pt real FFT (unnormalized), packed output [Re0,Re1,Re2,Re3,Re4,Im3,Im2,Im1]
__device__ __forceinline__ void rfft8p(float& x0, float& x1, float& x2, float& x3,
                                       float& x4, float& x5, float& x6, float& x7) {
  const float Cc = 0.70710678118654752f;
  float b0 = x0 + x4, b1 = x1 + x5, b2 = x2 + x6, b3 = x3 + x7;
  float d0 = x0 - x4, d1 = x1 - x5, d2 = x2 - x6, d3 = x3 - x7;
  float e0 = b0 + b2, e1 = b1 + b3, f0 = b0 - b2, f1 = b1 - b3;
  float t1 = Cc * (d1 - d3), t2 = Cc * (d1 + d3);
  x0 = e0 + e1; x4 = e0 - e1;
  x2 = f0;      x6 = -f1;
  x1 = d0 + t1; x7 = -(t2 + d2);
  x3 = d0 - t1; x5 = d2 - t2;
}

__device__ __forceinline__ void irfft8p(float& x0, float& x1, float& x2, float& x3,
                                        float& x4, float& x5, float& x6, float& x7) {
  const float Cc = 0.70710678118654752f;
  float R0 = x0, R1 = x1, R2 = x2, R3 = x3, R4 = x4, I3 = x5, I2 = x6, I1 = x7;
  float p = R0 + R4, q = R0 - R4;
  float u = 2.f * R2, vv = 2.f * I2;
  float g1 = R1 + R3, g2 = R1 - R3, g3 = I1 + I3, g4 = I1 - I3;
  float E1 = p + u, E2 = p - u;
  float B1 = 2.f * g1, B2 = 2.f * g4;
  float A1 = 2.f * Cc * (g2 - g3), A2c_ = 2.f * Cc * (g2 + g3);
  x0 = E1 + B1;  x4 = E1 - B1;
  x2 = E2 - B2;  x6 = E2 + B2;
  x1 = q + A1 - vv;  x5 = q - A1 - vv;
  x3 = q - A2c_ + vv;  x7 = q + A2c_ + vv;
}

template<bool INV>
__device__ __forceinline__ void cfft8(
    float& r0, float& r1, float& r2, float& r3, float& r4, float& r5, float& r6, float& r7,
    float& i0, float& i1, float& i2, float& i3, float& i4, float& i5, float& i6, float& i7) {
  const float Cc = 0.70710678118654752f;
  float s0r = r0 + r4, s0i = i0 + i4, s1r = r2 + r6, s1i = i2 + i6;
  float t0r = r0 - r4, t0i = i0 - i4, t1r = r2 - r6, t1i = i2 - i6;
  float E0r = s0r + s1r, E0i = s0i + s1i;
  float E2r = s0r - s1r, E2i = s0i - s1i;
  float E1r, E1i, E3r, E3i;
  if (!INV) { E1r = t0r + t1i; E1i = t0i - t1r; E3r = t0r - t1i; E3i = t0i + t1r; }
  else      { E1r = t0r - t1i; E1i = t0i + t1r; E3r = t0r + t1i; E3i = t0i - t1r; }
  float u0r = r1 + r5, u0i = i1 + i5, u1r = r3 + r7, u1i = i3 + i7;
  float p0r = r1 - r5, p0i = i1 - i5, p1r = r3 - r7, p1i = i3 - i7;
  float O0r = u0r + u1r, O0i = u0i + u1i;
  float O2r = u0r - u1r, O2i = u0i - u1i;
  float O1r, O1i, O3r, O3i;
  if (!INV) { O1r = p0r + p1i; O1i = p0i - p1r; O3r = p0r - p1i; O3i = p0i + p1r; }
  else      { O1r = p0r - p1i; O1i = p0i + p1r; O3r = p0r + p1i; O3i = p0i - p1r; }
  float W1r, W1i, W2r, W2i, W3r, W3i;
  if (!INV) {
    W1r = Cc * (O1r + O1i); W1i = Cc * (O1i - O1r);
    W2r = O2i;              W2i = -O2r;
    W3r = Cc * (O3i - O3r); W3i = -Cc * (O3r + O3i);
  } else {
    W1r = Cc * (O1r - O1i); W1i = Cc * (O1i + O1r);
    W2r = -O2i;             W2i = O2r;
    W3r = -Cc * (O3r + O3i); W3i = Cc * (O3r - O3i);
  }
  r0 = E0r + O0r; i0 = E0i + O0i;  r4 = E0r - O0r; i4 = E0i - O0i;
  r1 = E1r + W1r; i1 = E1i + W1i;  r5 = E1r - W1r; i5 = E1i - W1i;
  r2 = E2r + W2r; i2 = E2i + W2i;  r6 = E2r - W2r; i6 = E2i - W2i;
  r3 = E3r + W3r; i3 = E3i + W3i;  r7 = E3r - W3r; i7 = E3i - W3i;
}

// ---------------- K0: proj_w f32 -> bf16 in MFMA B-fragment layout ----------------
__global__ __launch_bounds__(256) void k_convert_proj(const float* __restrict__ p,
                                                      unsigned short* __restrict__ pb) {
  int t = blockIdx.x * 256 + threadIdx.x;
  int o = t / 96, cb = t - o * 96;
  const float* src = p + o * 768 + cb * 8;
  float4v v0 = *(const float4v*)(src);
  float4v v1 = *(const float4v*)(src + 4);
  ushort8v w;
#pragma unroll
  for (int r = 0; r < 4; ++r) { w[r] = f2bf(v0[r]); w[r + 4] = f2bf(v1[r]); }
  int ks = cb >> 2, g = cb & 3;
  int nf = o >> 4, l15 = o & 15;
  size_t off = ((size_t)(ks * 48 + nf) * 64 + g * 16 + l15) * 8;
  *(ushort8v*)(pb + off) = w;
}

// ---------------- K0b: pre-transpose + symmetrize spectral weights ----------------
__global__ __launch_bounds__(256) void k_prep_w(const float* __restrict__ wre,
                                                const float* __restrict__ wim,
                                                float* __restrict__ wT0,
                                                float* __restrict__ wT1) {
  int i = blockIdx.x * 256 + threadIdx.x;   // 40*768 = 30720
  if (i >= 40 * 768) return;
  int k = i / 768, c = i - k * 768;
  int h = k / 5, w = k - h * 5;
  const float S = 1.0f / 64.0f;
  const float* wr = wre + c * 40;
  const float* wi = wim + c * 40;
  float ar, ai;
  if (w == 0 || w == 4) {
    if (h == 0 || h == 4)      { ar = wr[k] * S; ai = 0.f; }
    else if (h <= 3)           { ar = (wr[h * 5 + w] + wr[(8 - h) * 5 + w]) * (0.5f * S);
                                 ai = (wi[h * 5 + w] - wi[(8 - h) * 5 + w]) * (0.5f * S); }
    else                       { ar = 0.f; ai = 0.f; }
  } else                       { ar = wr[k] * S; ai = wi[k] * S; }
  wT0[i] = ar; wT1[i] = ai;
}

// ---------------- fused persistent kernel ----------------
__device__ __forceinline__ float gelu_fast(float x) {
  float p = x * x;
  float q = fmaf(p, -0.1029434f, -2.3022082f);
  float e = exp2f(x * q);
  return x * __builtin_amdgcn_rcpf(1.0f + e);
}

__device__ __forceinline__ void fft_tile(const float* __restrict__ xb, int c,
                                         const float* __restrict__ wT0,
                                         const float* __restrict__ wT1,
                                         unsigned short* A2) {
  float v[8][8];
#pragma unroll
  for (int m = 0; m < 8; ++m)
#pragma unroll
    for (int n = 0; n < 8; ++n) v[m][n] = xb[(m * 8 + n) * C_DIM + c];

#define ROWV(m) v[m][0], v[m][1], v[m][2], v[m][3], v[m][4], v[m][5], v[m][6], v[m][7]
#define COLV(w) v[0][w], v[1][w], v[2][w], v[3][w], v[4][w], v[5][w], v[6][w], v[7][w]
#pragma unroll
  for (int m = 0; m < 8; ++m) rfft8p(ROWV(m));
  rfft8p(COLV(0));
  rfft8p(COLV(4));
  cfft8<false>(COLV(1), COLV(7));
  cfft8<false>(COLV(2), COLV(6));
  cfft8<false>(COLV(3), COLV(5));

#define LR(k) wT0[(k) * 768 + c]
#define LI(k) wT1[(k) * 768 + c]
#pragma unroll
  for (int w = 0; w <= 4; w += 4) {
    v[0][w] *= LR(w);
    v[4][w] *= LR(20 + w);
#pragma unroll
    for (int h = 1; h <= 3; ++h) {
      float ar = LR(h * 5 + w), ai = LI(h * 5 + w);
      float re = v[h][w], im = v[8 - h][w];
      v[h][w]     = re * ar - im * ai;
      v[8 - h][w] = re * ai + im * ar;
    }
  }
#pragma unroll
  for (int w = 1; w <= 3; ++w) {
#pragma unroll
    for (int h = 0; h < 8; ++h) {
      float ar = LR(h * 5 + w), ai = LI(h * 5 + w);
      float re = v[h][w], im = v[h][8 - w];
      v[h][w]     = re * ar - im * ai;
      v[h][8 - w] = re * ai + im * ar;
    }
  }
#undef LR
#undef LI

  irfft8p(COLV(0));
  irfft8p(COLV(4));
  cfft8<true>(COLV(1), COLV(7));
  cfft8<true>(COLV(2), COLV(6));
  cfft8<true>(COLV(3), COLV(5));
#pragma unroll
  for (int m = 0; m < 8; ++m) irfft8p(ROWV(m));
#undef ROWV
#undef COLV

  // A2[hw][c] bf16, byte XOR-swizzle ((hw&7)<<4)
  char* base = (char*)A2;
#pragma unroll
  for (int m = 0; m < 8; ++m)
#pragma unroll
    for (int n = 0; n < 8; ++n) {
      const int hw = m * 8 + n;
      int off = (hw * 1536 + c * 2) ^ ((hw & 7) << 4);
      *(unsigned short*)(base + off) = f2bf(v[m][n]);
    }
}

__global__ __launch_bounds__(1024, 4) void k_fused(const float* __restrict__ x,
                                                   const float* __restrict__ wT0,
                                                   const float* __restrict__ wT1,
                                                   const unsigned short* __restrict__ projB,
                                                   const float* __restrict__ gnw,
                                                   const float* __restrict__ gnb,
                                                   float* __restrict__ out, int B) {
  __shared__ __align__(16) unsigned short A2[64 * 768];  // 96 KB
  __shared__ float redS[2][16], redQ[2][16];

  const int tid  = threadIdx.x;
  const int wid  = tid >> 6;        // 0..15, wave owns o in [wid*48, wid*48+48)
  const int lane = tid & 63;
  const int g    = lane >> 4;
  const int l15  = lane & 15;

  const unsigned short* Bb = projB + ((size_t)(wid * 3) * 64 + lane) * 8;
  const char* A2c = (const char*)A2;
  const int swz = (l15 & 7) << 4;

#define LOADB(BF, KS)                                                        \
  do {                                                                       \
    _Pragma("unroll") for (int nf = 0; nf < 3; ++nf)                         \
        BF[nf] = *(const short8v*)&Bb[(KS) * 24576 + nf * 512];              \
  } while (0)

#define LOADA(AF, KS)                                                        \
  do {                                                                       \
    _Pragma("unroll") for (int mf = 0; mf < 4; ++mf)                         \
        AF[mf] = *(const short8v*)(A2c +                                     \
            (((mf * 16 + l15) * 1536 + (KS) * 64 + g * 16) ^ swz));          \
  } while (0)

#define MFMAS(AF, BF)                                                        \
  do {                                                                       \
    _Pragma("unroll") for (int mf = 0; mf < 4; ++mf)                         \
        _Pragma("unroll") for (int nf = 0; nf < 3; ++nf)                     \
            acc[mf][nf] = __builtin_amdgcn_mfma_f32_16x16x32_bf16(           \
                __builtin_bit_cast(bf16x8, AF[mf]), __builtin_bit_cast(bf16x8, BF[nf]),\
                acc[mf][nf], 0, 0, 0);                                       \
  } while (0)

  int par = 0;
  for (int b = blockIdx.x; b < B; b += 256) {
    short8v b0[3], b1[3], b2[3], aR[4];
    // prefetch first B k-step; latency hides under the FFT phase
    LOADB(b0, 0);

    const float* xb = x + (size_t)b * NEL;
    if (tid < 768) fft_tile(xb, tid, wT0, wT1, A2);
    __syncthreads();

    f32x4 acc[4][3];
#pragma unroll
    for (int mf = 0; mf < 4; ++mf)
#pragma unroll
      for (int nf = 0; nf < 3; ++nf) acc[mf][nf] = f32x4{0.f, 0.f, 0.f, 0.f};

    LOADB(b1, 1);
#pragma unroll 1
    for (int ks = 0; ks < 21; ks += 3) {
      LOADB(b2, ks + 2);
      LOADA(aR, ks);     MFMAS(aR, b0);
      LOADB(b0, ks + 3);
      LOADA(aR, ks + 1); MFMAS(aR, b1);
      LOADB(b1, ks + 4);
      LOADA(aR, ks + 2); MFMAS(aR, b2);
    }
    LOADB(b2, 23);
    LOADA(aR, 21); MFMAS(aR, b0);
    LOADA(aR, 22); MFMAS(aR, b1);
    LOADA(aR, 23); MFMAS(aR, b2);

    // ---- GroupNorm stats (deterministic in-block reduction) ----
    float s = 0.f, ss = 0.f;
#pragma unroll
    for (int mf = 0; mf < 4; ++mf)
#pragma unroll
      for (int nf = 0; nf < 3; ++nf)
#pragma unroll
        for (int r = 0; r < 4; ++r) {
          float t = acc[mf][nf][r];
          s += t;
          ss += t * t;
        }
#pragma unroll
    for (int off = 32; off > 0; off >>= 1) {
      s  += __shfl_xor(s, off, 64);
      ss += __shfl_xor(ss, off, 64);
    }
    if (lane == 0) { redS[par][wid] = s; redQ[par][wid] = ss; }
    __syncthreads();
    float Stot = 0.f, Qtot = 0.f;
#pragma unroll
    for (int i = 0; i < 16; ++i) { Stot += redS[par][i]; Qtot += redQ[par][i]; }
    constexpr float invN = 1.0f / 49152.0f;
    const float mean = Stot * invN;
    const float inv  = rsqrtf(fmaxf(Qtot * invN - mean * mean, 0.f) + 1e-5f);

    // ---- GN + GELU, write out[b][hw][o]; stores drain under next b's FFT ----
    float* outb = out + (size_t)b * NEL;
#pragma unroll
    for (int nf = 0; nf < 3; ++nf) {
      const int o = wid * 48 + nf * 16 + l15;
      const float gw = gnw[o], gb_ = gnb[o];
#pragma unroll
      for (int mf = 0; mf < 4; ++mf)
#pragma unroll
        for (int r = 0; r < 4; ++r) {
          const int hw = mf * 16 + g * 4 + r;
          float t = (acc[mf][nf][r] - mean) * inv;
          t = t * gw + gb_;
          outb[(size_t)hw * O_DIM + o] = gelu_fast(t);
        }
    }
    par ^= 1;
  }
#undef LOADA
#undef LOADB
#undef MFMAS
}

extern "C" void kernel_launch(void* const* d_in, const int* in_sizes, int n_in,
                              void* d_out, int out_size, void* d_ws, size_t ws_size,
                              hipStream_t stream) {
  const float* x   = (const float*)d_in[0];
  const float* wre = (const float*)d_in[1];
  const float* wim = (const float*)d_in[2];
  const float* pw  = (const float*)d_in[3];
  const float* gnw = (const float*)d_in[4];
  const float* gnb = (const float*)d_in[5];
  float* out = (float*)d_out;

  const int B = in_sizes[0] / NEL;  // 1024

  unsigned short* projB = (unsigned short*)d_ws;
  float* wT0 = (float*)((char*)d_ws + (2u << 20));
  float* wT1 = (float*)((char*)d_ws + (2u << 20) + (256u << 10));

  k_convert_proj<<<288, 256, 0, stream>>>(pw, projB);
  k_prep_w<<<120, 256, 0, stream>>>(wre, wim, wT0, wT1);
  k_fused<<<256, 1024, 0, stream>>>(x, wT0, wT1, projB, gnw, gnb, out, B);
}

// Round 7
// 363.076 us; speedup vs baseline: 1.4745x; 1.4745x over previous
//
#include <hip/hip_runtime.h>
#include <cstddef>

typedef __attribute__((ext_vector_type(4))) float  float4v;
typedef __attribute__((ext_vector_type(8))) short  short8v;
typedef __attribute__((ext_vector_type(8))) unsigned short ushort8v;
typedef __attribute__((ext_vector_type(8))) __bf16 bf16x8;
typedef __attribute__((ext_vector_type(4))) float  f32x4;

static constexpr int C_DIM = 768;
static constexpr int O_DIM = 768;
static constexpr int NEL   = 49152;  // 768*64

__device__ __forceinline__ unsigned short f2bf(float f) {
  __bf16 h = (__bf16)f;
  return __builtin_bit_cast(unsigned short, h);
}

// forward 8-pt real FFT (unnormalized), packed output [Re0,Re1,Re2,Re3,Re4,Im3,Im2,Im1]
__device__ __forceinline__ void rfft8p(float& x0, float& x1, float& x2, float& x3,
                                       float& x4, float& x5, float& x6, float& x7) {
  const float Cc = 0.70710678118654752f;
  float b0 = x0 + x4, b1 = x1 + x5, b2 = x2 + x6, b3 = x3 + x7;
  float d0 = x0 - x4, d1 = x1 - x5, d2 = x2 - x6, d3 = x3 - x7;
  float e0 = b0 + b2, e1 = b1 + b3, f0 = b0 - b2, f1 = b1 - b3;
  float t1 = Cc * (d1 - d3), t2 = Cc * (d1 + d3);
  x0 = e0 + e1; x4 = e0 - e1;
  x2 = f0;      x6 = -f1;
  x1 = d0 + t1; x7 = -(t2 + d2);
  x3 = d0 - t1; x5 = d2 - t2;
}

__device__ __forceinline__ void irfft8p(float& x0, float& x1, float& x2, float& x3,
                                        float& x4, float& x5, float& x6, float& x7) {
  const float Cc = 0.70710678118654752f;
  float R0 = x0, R1 = x1, R2 = x2, R3 = x3, R4 = x4, I3 = x5, I2 = x6, I1 = x7;
  float p = R0 + R4, q = R0 - R4;
  float u = 2.f * R2, vv = 2.f * I2;
  float g1 = R1 + R3, g2 = R1 - R3, g3 = I1 + I3, g4 = I1 - I3;
  float E1 = p + u, E2 = p - u;
  float B1 = 2.f * g1, B2 = 2.f * g4;
  float A1 = 2.f * Cc * (g2 - g3), A2c_ = 2.f * Cc * (g2 + g3);
  x0 = E1 + B1;  x4 = E1 - B1;
  x2 = E2 - B2;  x6 = E2 + B2;
  x1 = q + A1 - vv;  x5 = q - A1 - vv;
  x3 = q - A2c_ + vv;  x7 = q + A2c_ + vv;
}

template<bool INV>
__device__ __forceinline__ void cfft8(
    float& r0, float& r1, float& r2, float& r3, float& r4, float& r5, float& r6, float& r7,
    float& i0, float& i1, float& i2, float& i3, float& i4, float& i5, float& i6, float& i7) {
  const float Cc = 0.70710678118654752f;
  float s0r = r0 + r4, s0i = i0 + i4, s1r = r2 + r6, s1i = i2 + i6;
  float t0r = r0 - r4, t0i = i0 - i4, t1r = r2 - r6, t1i = i2 - i6;
  float E0r = s0r + s1r, E0i = s0i + s1i;
  float E2r = s0r - s1r, E2i = s0i - s1i;
  float E1r, E1i, E3r, E3i;
  if (!INV) { E1r = t0r + t1i; E1i = t0i - t1r; E3r = t0r - t1i; E3i = t0i + t1r; }
  else      { E1r = t0r - t1i; E1i = t0i + t1r; E3r = t0r + t1i; E3i = t0i - t1r; }
  float u0r = r1 + r5, u0i = i1 + i5, u1r = r3 + r7, u1i = i3 + i7;
  float p0r = r1 - r5, p0i = i1 - i5, p1r = r3 - r7, p1i = i3 - i7;
  float O0r = u0r + u1r, O0i = u0i + u1i;
  float O2r = u0r - u1r, O2i = u0i - u1i;
  float O1r, O1i, O3r, O3i;
  if (!INV) { O1r = p0r + p1i; O1i = p0i - p1r; O3r = p0r - p1i; O3i = p0i + p1r; }
  else      { O1r = p0r - p1i; O1i = p0i + p1r; O3r = p0r + p1i; O3i = p0i - p1r; }
  float W1r, W1i, W2r, W2i, W3r, W3i;
  if (!INV) {
    W1r = Cc * (O1r + O1i); W1i = Cc * (O1i - O1r);
    W2r = O2i;              W2i = -O2r;
    W3r = Cc * (O3i - O3r); W3i = -Cc * (O3r + O3i);
  } else {
    W1r = Cc * (O1r - O1i); W1i = Cc * (O1i + O1r);
    W2r = -O2i;             W2i = O2r;
    W3r = -Cc * (O3r + O3i); W3i = Cc * (O3r - O3i);
  }
  r0 = E0r + O0r; i0 = E0i + O0i;  r4 = E0r - O0r; i4 = E0i - O0i;
  r1 = E1r + W1r; i1 = E1i + W1i;  r5 = E1r - W1r; i5 = E1i - W1i;
  r2 = E2r + W2r; i2 = E2i + W2i;  r6 = E2r - W2r; i6 = E2i - W2i;
  r3 = E3r + W3r; i3 = E3i + W3i;  r7 = E3r - W3r; i7 = E3i - W3i;
}

// ---------------- K0: proj_w f32 -> bf16 in MFMA B-fragment layout ----------------
__global__ __launch_bounds__(256) void k_convert_proj(const float* __restrict__ p,
                                                      unsigned short* __restrict__ pb) {
  int t = blockIdx.x * 256 + threadIdx.x;
  int o = t / 96, cb = t - o * 96;
  const float* src = p + o * 768 + cb * 8;
  float4v v0 = *(const float4v*)(src);
  float4v v1 = *(const float4v*)(src + 4);
  ushort8v w;
#pragma unroll
  for (int r = 0; r < 4; ++r) { w[r] = f2bf(v0[r]); w[r + 4] = f2bf(v1[r]); }
  int ks = cb >> 2, g = cb & 3;
  int nf = o >> 4, l15 = o & 15;
  size_t off = ((size_t)(ks * 48 + nf) * 64 + g * 16 + l15) * 8;
  *(ushort8v*)(pb + off) = w;
}

// ---------------- K0b: pre-transpose + symmetrize spectral weights ----------------
__global__ __launch_bounds__(256) void k_prep_w(const float* __restrict__ wre,
                                                const float* __restrict__ wim,
                                                float* __restrict__ wT0,
                                                float* __restrict__ wT1) {
  int i = blockIdx.x * 256 + threadIdx.x;   // 40*768 = 30720
  if (i >= 40 * 768) return;
  int k = i / 768, c = i - k * 768;
  int h = k / 5, w = k - h * 5;
  const float S = 1.0f / 64.0f;
  const float* wr = wre + c * 40;
  const float* wi = wim + c * 40;
  float ar, ai;
  if (w == 0 || w == 4) {
    if (h == 0 || h == 4)      { ar = wr[k] * S; ai = 0.f; }
    else if (h <= 3)           { ar = (wr[h * 5 + w] + wr[(8 - h) * 5 + w]) * (0.5f * S);
                                 ai = (wi[h * 5 + w] - wi[(8 - h) * 5 + w]) * (0.5f * S); }
    else                       { ar = 0.f; ai = 0.f; }
  } else                       { ar = wr[k] * S; ai = wi[k] * S; }
  wT0[i] = ar; wT1[i] = ai;
}

// ---------------- fused persistent kernel ----------------
__device__ __forceinline__ float gelu_fast(float x) {
  float p = x * x;
  float q = fmaf(p, -0.1029434f, -2.3022082f);
  float e = exp2f(x * q);
  return x * __builtin_amdgcn_rcpf(1.0f + e);
}

__global__ __launch_bounds__(1024, 4) void k_fused(const float* __restrict__ x,
                                                   const float* __restrict__ wT0,
                                                   const float* __restrict__ wT1,
                                                   const unsigned short* __restrict__ projB,
                                                   const float* __restrict__ gnw,
                                                   const float* __restrict__ gnb,
                                                   float* __restrict__ out, int B) {
  __shared__ __align__(16) unsigned short A2[64 * 768];  // 96 KB
  __shared__ float F[128 * 65];                          // 33.3 KB (pad 65: conflict-free)
  __shared__ float redS[2][16], redQ[2][16];

  const int tid  = threadIdx.x;
  const int wid  = tid >> 6;        // 0..15, wave owns o in [wid*48, wid*48+48)
  const int lane = tid & 63;
  const int g    = lane >> 4;
  const int l15  = lane & 15;

  // FFT mapping: thread = (row fm, channel-local cl); wave-uniform fm
  const int cl = tid & 127;
  const int fm = tid >> 7;          // 0..7

  const unsigned short* Bb = projB + ((size_t)(wid * 3) * 64 + lane) * 8;
  const char* A2c = (const char*)A2;
  const int swz = (l15 & 7) << 4;

#define LOADB(BF, KS)                                                        \
  do {                                                                       \
    _Pragma("unroll") for (int nf = 0; nf < 3; ++nf)                         \
        BF[nf] = *(const short8v*)&Bb[(KS) * 24576 + nf * 512];              \
  } while (0)

#define LOADA(AF, KS)                                                        \
  do {                                                                       \
    _Pragma("unroll") for (int mf = 0; mf < 4; ++mf)                         \
        AF[mf] = *(const short8v*)(A2c +                                     \
            (((mf * 16 + l15) * 1536 + (KS) * 64 + g * 16) ^ swz));          \
  } while (0)

#define MFMAS(AF, BF)                                                        \
  do {                                                                       \
    _Pragma("unroll") for (int mf = 0; mf < 4; ++mf)                         \
        _Pragma("unroll") for (int nf = 0; nf < 3; ++nf)                     \
            acc[mf][nf] = __builtin_amdgcn_mfma_f32_16x16x32_bf16(           \
                __builtin_bit_cast(bf16x8, AF[mf]), __builtin_bit_cast(bf16x8, BF[nf]),\
                acc[mf][nf], 0, 0, 0);                                       \
  } while (0)

  int par = 0;
  for (int b = blockIdx.x; b < B; b += 256) {
    short8v bB0[3], bB1[3], aR[4];
    LOADB(bB0, 0);                      // covered by chunk-0 FFT

    const float* xb = x + (size_t)b * NEL;
    // prefetch x chunk 0 (row fm, channel cl)
    float xr[8];
#pragma unroll
    for (int n = 0; n < 8; ++n) xr[n] = xb[(fm * 8 + n) * C_DIM + cl];

    f32x4 acc[4][3];
#pragma unroll
    for (int mf = 0; mf < 4; ++mf)
#pragma unroll
      for (int nf = 0; nf < 3; ++nf) acc[mf][nf] = f32x4{0.f, 0.f, 0.f, 0.f};

#pragma unroll 1
    for (int j = 0; j < 6; ++j) {
      const int ch = j * 128 + cl;
      // ---- phase 1: row FFT, write packed rows to F ----
      rfft8p(xr[0], xr[1], xr[2], xr[3], xr[4], xr[5], xr[6], xr[7]);
#pragma unroll
      for (int n = 0; n < 8; ++n) F[cl * 65 + fm * 8 + n] = xr[n];
      if (j < 5) {
#pragma unroll
        for (int n = 0; n < 8; ++n) xr[n] = xb[(fm * 8 + n) * C_DIM + ch + 128];
      }
      __syncthreads();

      // ---- phase 2: column FFT + weights + inverse column FFT ----
      if (fm == 0 || fm == 4) {
        const int w = fm;
        float a0 = F[cl * 65 + 0 * 8 + w], a1 = F[cl * 65 + 1 * 8 + w];
        float a2 = F[cl * 65 + 2 * 8 + w], a3 = F[cl * 65 + 3 * 8 + w];
        float a4 = F[cl * 65 + 4 * 8 + w], a5 = F[cl * 65 + 5 * 8 + w];
        float a6 = F[cl * 65 + 6 * 8 + w], a7 = F[cl * 65 + 7 * 8 + w];
        rfft8p(a0, a1, a2, a3, a4, a5, a6, a7);
        a0 *= wT0[(0 * 5 + w) * 768 + ch];
        a4 *= wT0[(4 * 5 + w) * 768 + ch];
        {
          float ar = wT0[(1 * 5 + w) * 768 + ch], ai = wT1[(1 * 5 + w) * 768 + ch];
          float re = a1, im = a7; a1 = re * ar - im * ai; a7 = re * ai + im * ar;
        }
        {
          float ar = wT0[(2 * 5 + w) * 768 + ch], ai = wT1[(2 * 5 + w) * 768 + ch];
          float re = a2, im = a6; a2 = re * ar - im * ai; a6 = re * ai + im * ar;
        }
        {
          float ar = wT0[(3 * 5 + w) * 768 + ch], ai = wT1[(3 * 5 + w) * 768 + ch];
          float re = a3, im = a5; a3 = re * ar - im * ai; a5 = re * ai + im * ar;
        }
        irfft8p(a0, a1, a2, a3, a4, a5, a6, a7);
        F[cl * 65 + 0 * 8 + w] = a0; F[cl * 65 + 1 * 8 + w] = a1;
        F[cl * 65 + 2 * 8 + w] = a2; F[cl * 65 + 3 * 8 + w] = a3;
        F[cl * 65 + 4 * 8 + w] = a4; F[cl * 65 + 5 * 8 + w] = a5;
        F[cl * 65 + 6 * 8 + w] = a6; F[cl * 65 + 7 * 8 + w] = a7;
      } else if (fm <= 3) {
        const int w = fm;
        float cr[8], ci[8];
#pragma unroll
        for (int h = 0; h < 8; ++h) {
          cr[h] = F[cl * 65 + h * 8 + w];
          ci[h] = F[cl * 65 + h * 8 + (8 - w)];
        }
        cfft8<false>(cr[0], cr[1], cr[2], cr[3], cr[4], cr[5], cr[6], cr[7],
                     ci[0], ci[1], ci[2], ci[3], ci[4], ci[5], ci[6], ci[7]);
#pragma unroll
        for (int h = 0; h < 8; ++h) {
          float ar = wT0[(h * 5 + w) * 768 + ch], ai = wT1[(h * 5 + w) * 768 + ch];
          float re = cr[h], im = ci[h];
          cr[h] = re * ar - im * ai;
          ci[h] = re * ai + im * ar;
        }
        cfft8<true>(cr[0], cr[1], cr[2], cr[3], cr[4], cr[5], cr[6], cr[7],
                    ci[0], ci[1], ci[2], ci[3], ci[4], ci[5], ci[6], ci[7]);
#pragma unroll
        for (int h = 0; h < 8; ++h) {
          F[cl * 65 + h * 8 + w]       = cr[h];
          F[cl * 65 + h * 8 + (8 - w)] = ci[h];
        }
      }
      __syncthreads();

      // ---- phase 3: inverse row FFT, write A2 (swizzled bf16) ----
      {
        float r0 = F[cl * 65 + fm * 8 + 0], r1 = F[cl * 65 + fm * 8 + 1];
        float r2 = F[cl * 65 + fm * 8 + 2], r3 = F[cl * 65 + fm * 8 + 3];
        float r4 = F[cl * 65 + fm * 8 + 4], r5 = F[cl * 65 + fm * 8 + 5];
        float r6 = F[cl * 65 + fm * 8 + 6], r7 = F[cl * 65 + fm * 8 + 7];
        irfft8p(r0, r1, r2, r3, r4, r5, r6, r7);
        char* base = (char*)A2;
        float rr[8] = {r0, r1, r2, r3, r4, r5, r6, r7};
#pragma unroll
        for (int n = 0; n < 8; ++n) {
          const int hw = fm * 8 + n;
          int off = (hw * 1536 + ch * 2) ^ ((hw & 7) << 4);
          *(unsigned short*)(base + off) = f2bf(rr[n]);
        }
      }
      __syncthreads();

      // ---- GEMM group: k-steps 4j .. 4j+3 (B prefetched one ahead) ----
      {
        const int k0 = j * 4;
        LOADB(bB1, k0 + 1);
        LOADA(aR, k0);     MFMAS(aR, bB0);
        LOADB(bB0, k0 + 2);
        LOADA(aR, k0 + 1); MFMAS(aR, bB1);
        LOADB(bB1, k0 + 3);
        LOADA(aR, k0 + 2); MFMAS(aR, bB0);
        if (j < 5) LOADB(bB0, k0 + 4);
        LOADA(aR, k0 + 3); MFMAS(aR, bB1);
      }
    }

    // ---- GroupNorm stats (deterministic in-block reduction) ----
    float s = 0.f, ss = 0.f;
#pragma unroll
    for (int mf = 0; mf < 4; ++mf)
#pragma unroll
      for (int nf = 0; nf < 3; ++nf)
#pragma unroll
        for (int r = 0; r < 4; ++r) {
          float t = acc[mf][nf][r];
          s += t;
          ss += t * t;
        }
#pragma unroll
    for (int off = 32; off > 0; off >>= 1) {
      s  += __shfl_xor(s, off, 64);
      ss += __shfl_xor(ss, off, 64);
    }
    if (lane == 0) { redS[par][wid] = s; redQ[par][wid] = ss; }
    __syncthreads();
    float Stot = 0.f, Qtot = 0.f;
#pragma unroll
    for (int i = 0; i < 16; ++i) { Stot += redS[par][i]; Qtot += redQ[par][i]; }
    constexpr float invN = 1.0f / 49152.0f;
    const float mean = Stot * invN;
    const float inv  = rsqrtf(fmaxf(Qtot * invN - mean * mean, 0.f) + 1e-5f);

    // ---- GN + GELU, write out[b][hw][o]; stores drain under next b's FFT ----
    float* outb = out + (size_t)b * NEL;
#pragma unroll
    for (int nf = 0; nf < 3; ++nf) {
      const int o = wid * 48 + nf * 16 + l15;
      const float gw = gnw[o], gb_ = gnb[o];
#pragma unroll
      for (int mf = 0; mf < 4; ++mf)
#pragma unroll
        for (int r = 0; r < 4; ++r) {
          const int hw = mf * 16 + g * 4 + r;
          float t = (acc[mf][nf][r] - mean) * inv;
          t = t * gw + gb_;
          outb[(size_t)hw * O_DIM + o] = gelu_fast(t);
        }
    }
    par ^= 1;
  }
#undef LOADA
#undef LOADB
#undef MFMAS
}

extern "C" void kernel_launch(void* const* d_in, const int* in_sizes, int n_in,
                              void* d_out, int out_size, void* d_ws, size_t ws_size,
                              hipStream_t stream) {
  const float* x   = (const float*)d_in[0];
  const float* wre = (const float*)d_in[1];
  const float* wim = (const float*)d_in[2];
  const float* pw  = (const float*)d_in[3];
  const float* gnw = (const float*)d_in[4];
  const float* gnb = (const float*)d_in[5];
  float* out = (float*)d_out;

  const int B = in_sizes[0] / NEL;  // 1024

  unsigned short* projB = (unsigned short*)d_ws;
  float* wT0 = (float*)((char*)d_ws + (2u << 20));
  float* wT1 = (float*)((char*)d_ws + (2u << 20) + (256u << 10));

  k_convert_proj<<<288, 256, 0, stream>>>(pw, projB);
  k_prep_w<<<120, 256, 0, stream>>>(wre, wim, wT0, wT1);
  k_fused<<<256, 1024, 0, stream>>>(x, wT0, wT1, projB, gnw, gnb, out, B);
}

// Round 8
// 339.404 us; speedup vs baseline: 1.5774x; 1.0697x over previous
//
#include <hip/hip_runtime.h>
#include <cstddef>

typedef __attribute__((ext_vector_type(4))) float  float4v;
typedef __attribute__((ext_vector_type(8))) short  short8v;
typedef __attribute__((ext_vector_type(8))) unsigned short ushort8v;
typedef __attribute__((ext_vector_type(8))) __bf16 bf16x8;
typedef __attribute__((ext_vector_type(4))) float  f32x4;

static constexpr int C_DIM = 768;
static constexpr int O_DIM = 768;
static constexpr int NEL   = 49152;  // 768*64

__device__ __forceinline__ unsigned short f2bf(float f) {
  __bf16 h = (__bf16)f;
  return __builtin_bit_cast(unsigned short, h);
}

// forward 8-pt real FFT (unnormalized), packed output [Re0,Re1,Re2,Re3,Re4,Im3,Im2,Im1]
__device__ __forceinline__ void rfft8p(float& x0, float& x1, float& x2, float& x3,
                                       float& x4, float& x5, float& x6, float& x7) {
  const float Cc = 0.70710678118654752f;
  float b0 = x0 + x4, b1 = x1 + x5, b2 = x2 + x6, b3 = x3 + x7;
  float d0 = x0 - x4, d1 = x1 - x5, d2 = x2 - x6, d3 = x3 - x7;
  float e0 = b0 + b2, e1 = b1 + b3, f0 = b0 - b2, f1 = b1 - b3;
  float t1 = Cc * (d1 - d3), t2 = Cc * (d1 + d3);
  x0 = e0 + e1; x4 = e0 - e1;
  x2 = f0;      x6 = -f1;
  x1 = d0 + t1; x7 = -(t2 + d2);
  x3 = d0 - t1; x5 = d2 - t2;
}

__device__ __forceinline__ void irfft8p(float& x0, float& x1, float& x2, float& x3,
                                        float& x4, float& x5, float& x6, float& x7) {
  const float Cc = 0.70710678118654752f;
  float R0 = x0, R1 = x1, R2 = x2, R3 = x3, R4 = x4, I3 = x5, I2 = x6, I1 = x7;
  float p = R0 + R4, q = R0 - R4;
  float u = 2.f * R2, vv = 2.f * I2;
  float g1 = R1 + R3, g2 = R1 - R3, g3 = I1 + I3, g4 = I1 - I3;
  float E1 = p + u, E2 = p - u;
  float B1 = 2.f * g1, B2 = 2.f * g4;
  float A1 = 2.f * Cc * (g2 - g3), A2c_ = 2.f * Cc * (g2 + g3);
  x0 = E1 + B1;  x4 = E1 - B1;
  x2 = E2 - B2;  x6 = E2 + B2;
  x1 = q + A1 - vv;  x5 = q - A1 - vv;
  x3 = q - A2c_ + vv;  x7 = q + A2c_ + vv;
}

template<bool INV>
__device__ __forceinline__ void cfft8(
    float& r0, float& r1, float& r2, float& r3, float& r4, float& r5, float& r6, float& r7,
    float& i0, float& i1, float& i2, float& i3, float& i4, float& i5, float& i6, float& i7) {
  const float Cc = 0.70710678118654752f;
  float s0r = r0 + r4, s0i = i0 + i4, s1r = r2 + r6, s1i = i2 + i6;
  float t0r = r0 - r4, t0i = i0 - i4, t1r = r2 - r6, t1i = i2 - i6;
  float E0r = s0r + s1r, E0i = s0i + s1i;
  float E2r = s0r - s1r, E2i = s0i - s1i;
  float E1r, E1i, E3r, E3i;
  if (!INV) { E1r = t0r + t1i; E1i = t0i - t1r; E3r = t0r - t1i; E3i = t0i + t1r; }
  else      { E1r = t0r - t1i; E1i = t0i + t1r; E3r = t0r + t1i; E3i = t0i - t1r; }
  float u0r = r1 + r5, u0i = i1 + i5, u1r = r3 + r7, u1i = i3 + i7;
  float p0r = r1 - r5, p0i = i1 - i5, p1r = r3 - r7, p1i = i3 - i7;
  float O0r = u0r + u1r, O0i = u0i + u1i;
  float O2r = u0r - u1r, O2i = u0i - u1i;
  float O1r, O1i, O3r, O3i;
  if (!INV) { O1r = p0r + p1i; O1i = p0i - p1r; O3r = p0r - p1i; O3i = p0i + p1r; }
  else      { O1r = p0r - p1i; O1i = p0i + p1r; O3r = p0r + p1i; O3i = p0i - p1r; }
  float W1r, W1i, W2r, W2i, W3r, W3i;
  if (!INV) {
    W1r = Cc * (O1r + O1i); W1i = Cc * (O1i - O1r);
    W2r = O2i;              W2i = -O2r;
    W3r = Cc * (O3i - O3r); W3i = -Cc * (O3r + O3i);
  } else {
    W1r = Cc * (O1r - O1i); W1i = Cc * (O1i + O1r);
    W2r = -O2i;             W2i = O2r;
    W3r = -Cc * (O3r + O3i); W3i = Cc * (O3r - O3i);
  }
  r0 = E0r + O0r; i0 = E0i + O0i;  r4 = E0r - O0r; i4 = E0i - O0i;
  r1 = E1r + W1r; i1 = E1i + W1i;  r5 = E1r - W1r; i5 = E1i - W1i;
  r2 = E2r + W2r; i2 = E2i + W2i;  r6 = E2r - W2r; i6 = E2i - W2i;
  r3 = E3r + W3r; i3 = E3i + W3i;  r7 = E3r - W3r; i7 = E3i - W3i;
}

// ---------------- K0: proj_w f32 -> bf16 in MFMA B-fragment layout ----------------
__global__ __launch_bounds__(256) void k_convert_proj(const float* __restrict__ p,
                                                      unsigned short* __restrict__ pb) {
  int t = blockIdx.x * 256 + threadIdx.x;
  int o = t / 96, cb = t - o * 96;
  const float* src = p + o * 768 + cb * 8;
  float4v v0 = *(const float4v*)(src);
  float4v v1 = *(const float4v*)(src + 4);
  ushort8v w;
#pragma unroll
  for (int r = 0; r < 4; ++r) { w[r] = f2bf(v0[r]); w[r + 4] = f2bf(v1[r]); }
  int ks = cb >> 2, g = cb & 3;
  int nf = o >> 4, l15 = o & 15;
  size_t off = ((size_t)(ks * 48 + nf) * 64 + g * 16 + l15) * 8;
  *(ushort8v*)(pb + off) = w;
}

// ---------------- K0b: pre-transpose + symmetrize spectral weights ----------------
__global__ __launch_bounds__(256) void k_prep_w(const float* __restrict__ wre,
                                                const float* __restrict__ wim,
                                                float* __restrict__ wT0,
                                                float* __restrict__ wT1) {
  int i = blockIdx.x * 256 + threadIdx.x;   // 40*768 = 30720
  if (i >= 40 * 768) return;
  int k = i / 768, c = i - k * 768;
  int h = k / 5, w = k - h * 5;
  const float S = 1.0f / 64.0f;
  const float* wr = wre + c * 40;
  const float* wi = wim + c * 40;
  float ar, ai;
  if (w == 0 || w == 4) {
    if (h == 0 || h == 4)      { ar = wr[k] * S; ai = 0.f; }
    else if (h <= 3)           { ar = (wr[h * 5 + w] + wr[(8 - h) * 5 + w]) * (0.5f * S);
                                 ai = (wi[h * 5 + w] - wi[(8 - h) * 5 + w]) * (0.5f * S); }
    else                       { ar = 0.f; ai = 0.f; }
  } else                       { ar = wr[k] * S; ai = wi[k] * S; }
  wT0[i] = ar; wT1[i] = ai;
}

// ---------------- fused persistent kernel ----------------
__device__ __forceinline__ float gelu_fast(float x) {
  float p = x * x;
  float q = fmaf(p, -0.1029434f, -2.3022082f);
  float e = exp2f(x * q);
  return x * __builtin_amdgcn_rcpf(1.0f + e);
}

__global__ __launch_bounds__(768, 3) void k_fused(const float* __restrict__ x,
                                                  const float* __restrict__ wT0,
                                                  const float* __restrict__ wT1,
                                                  const unsigned short* __restrict__ projB,
                                                  const float* __restrict__ gnw,
                                                  const float* __restrict__ gnb,
                                                  float* __restrict__ out, int B) {
  __shared__ __align__(16) unsigned short A2[64 * 768];  // 96 KB
  __shared__ float F[96 * 65];                           // 24.96 KB (pad 65: conflict-free)
  __shared__ float redS[2][12], redQ[2][12];

  const int tid  = threadIdx.x;
  const int wid  = tid >> 6;        // 0..11, wave owns o in [wid*64, wid*64+64)
  const int lane = tid & 63;
  const int g    = lane >> 4;
  const int l15  = lane & 15;

  // FFT mapping: thread = (row fm = tid/96, channel-local cl = tid%96)
  const int fm = tid / 96;          // 0..7
  const int cl = tid - fm * 96;     // 0..95

  const unsigned short* Bb = projB + ((size_t)(wid * 4) * 64 + lane) * 8;
  const char* A2c = (const char*)A2;
  const int swz = (l15 & 7) << 4;

#define LOADB(BF, KS)                                                        \
  do {                                                                       \
    _Pragma("unroll") for (int nf = 0; nf < 4; ++nf)                         \
        BF[nf] = *(const short8v*)&Bb[(KS) * 24576 + nf * 512];              \
  } while (0)

#define LOADA(AF, KS)                                                        \
  do {                                                                       \
    _Pragma("unroll") for (int mf = 0; mf < 4; ++mf)                         \
        AF[mf] = *(const short8v*)(A2c +                                     \
            (((mf * 16 + l15) * 1536 + (KS) * 64 + g * 16) ^ swz));          \
  } while (0)

#define MFMAS(AF, BF)                                                        \
  do {                                                                       \
    _Pragma("unroll") for (int mf = 0; mf < 4; ++mf)                         \
        _Pragma("unroll") for (int nf = 0; nf < 4; ++nf)                     \
            acc[mf][nf] = __builtin_amdgcn_mfma_f32_16x16x32_bf16(           \
                __builtin_bit_cast(bf16x8, AF[mf]), __builtin_bit_cast(bf16x8, BF[nf]),\
                acc[mf][nf], 0, 0, 0);                                       \
  } while (0)

  int par = 0;
  for (int b = blockIdx.x; b < B; b += 256) {
    short8v bA[4], bBv[4], aR[4];
    LOADB(bA, 0);                       // held across chunk-0 FFT

    const float* xb = x + (size_t)b * NEL;
    // prefetch x chunk 0 (row fm, channel cl)
    float xr[8];
#pragma unroll
    for (int n = 0; n < 8; ++n) xr[n] = xb[(fm * 8 + n) * C_DIM + cl];

    f32x4 acc[4][4];
#pragma unroll
    for (int mf = 0; mf < 4; ++mf)
#pragma unroll
      for (int nf = 0; nf < 4; ++nf) acc[mf][nf] = f32x4{0.f, 0.f, 0.f, 0.f};

#pragma unroll 1
    for (int j = 0; j < 8; ++j) {
      const int ch = j * 96 + cl;
      // ---- phase 1: row FFT, write packed rows to F ----
      rfft8p(xr[0], xr[1], xr[2], xr[3], xr[4], xr[5], xr[6], xr[7]);
#pragma unroll
      for (int n = 0; n < 8; ++n) F[cl * 65 + fm * 8 + n] = xr[n];
      if (j < 7) {
#pragma unroll
        for (int n = 0; n < 8; ++n) xr[n] = xb[(fm * 8 + n) * C_DIM + ch + 96];
      }
      __syncthreads();

      // ---- phase 2: column FFT + weights + inverse column FFT ----
      if (fm == 0 || fm == 4) {
        const int w = fm;
        float a0 = F[cl * 65 + 0 * 8 + w], a1 = F[cl * 65 + 1 * 8 + w];
        float a2 = F[cl * 65 + 2 * 8 + w], a3 = F[cl * 65 + 3 * 8 + w];
        float a4 = F[cl * 65 + 4 * 8 + w], a5 = F[cl * 65 + 5 * 8 + w];
        float a6 = F[cl * 65 + 6 * 8 + w], a7 = F[cl * 65 + 7 * 8 + w];
        rfft8p(a0, a1, a2, a3, a4, a5, a6, a7);
        a0 *= wT0[(0 * 5 + w) * 768 + ch];
        a4 *= wT0[(4 * 5 + w) * 768 + ch];
        {
          float ar = wT0[(1 * 5 + w) * 768 + ch], ai = wT1[(1 * 5 + w) * 768 + ch];
          float re = a1, im = a7; a1 = re * ar - im * ai; a7 = re * ai + im * ar;
        }
        {
          float ar = wT0[(2 * 5 + w) * 768 + ch], ai = wT1[(2 * 5 + w) * 768 + ch];
          float re = a2, im = a6; a2 = re * ar - im * ai; a6 = re * ai + im * ar;
        }
        {
          float ar = wT0[(3 * 5 + w) * 768 + ch], ai = wT1[(3 * 5 + w) * 768 + ch];
          float re = a3, im = a5; a3 = re * ar - im * ai; a5 = re * ai + im * ar;
        }
        irfft8p(a0, a1, a2, a3, a4, a5, a6, a7);
        F[cl * 65 + 0 * 8 + w] = a0; F[cl * 65 + 1 * 8 + w] = a1;
        F[cl * 65 + 2 * 8 + w] = a2; F[cl * 65 + 3 * 8 + w] = a3;
        F[cl * 65 + 4 * 8 + w] = a4; F[cl * 65 + 5 * 8 + w] = a5;
        F[cl * 65 + 6 * 8 + w] = a6; F[cl * 65 + 7 * 8 + w] = a7;
      } else if (fm <= 3) {
        const int w = fm;
        float cr[8], ci[8];
#pragma unroll
        for (int h = 0; h < 8; ++h) {
          cr[h] = F[cl * 65 + h * 8 + w];
          ci[h] = F[cl * 65 + h * 8 + (8 - w)];
        }
        cfft8<false>(cr[0], cr[1], cr[2], cr[3], cr[4], cr[5], cr[6], cr[7],
                     ci[0], ci[1], ci[2], ci[3], ci[4], ci[5], ci[6], ci[7]);
#pragma unroll
        for (int h = 0; h < 8; ++h) {
          float ar = wT0[(h * 5 + w) * 768 + ch], ai = wT1[(h * 5 + w) * 768 + ch];
          float re = cr[h], im = ci[h];
          cr[h] = re * ar - im * ai;
          ci[h] = re * ai + im * ar;
        }
        cfft8<true>(cr[0], cr[1], cr[2], cr[3], cr[4], cr[5], cr[6], cr[7],
                    ci[0], ci[1], ci[2], ci[3], ci[4], ci[5], ci[6], ci[7]);
#pragma unroll
        for (int h = 0; h < 8; ++h) {
          F[cl * 65 + h * 8 + w]       = cr[h];
          F[cl * 65 + h * 8 + (8 - w)] = ci[h];
        }
      }
      __syncthreads();

      // ---- phase 3: inverse row FFT, write A2 (swizzled bf16) ----
      {
        float r0 = F[cl * 65 + fm * 8 + 0], r1 = F[cl * 65 + fm * 8 + 1];
        float r2 = F[cl * 65 + fm * 8 + 2], r3 = F[cl * 65 + fm * 8 + 3];
        float r4 = F[cl * 65 + fm * 8 + 4], r5 = F[cl * 65 + fm * 8 + 5];
        float r6 = F[cl * 65 + fm * 8 + 6], r7 = F[cl * 65 + fm * 8 + 7];
        irfft8p(r0, r1, r2, r3, r4, r5, r6, r7);
        char* base = (char*)A2;
        float rr[8] = {r0, r1, r2, r3, r4, r5, r6, r7};
#pragma unroll
        for (int n = 0; n < 8; ++n) {
          const int hw = fm * 8 + n;
          int off = (hw * 1536 + ch * 2) ^ ((hw & 7) << 4);
          *(unsigned short*)(base + off) = f2bf(rr[n]);
        }
      }
      __syncthreads();

      // ---- GEMM group: k-steps 3j .. 3j+2 (bA holds 3j; end holding 3j+3) ----
      {
        const int k0 = j * 3;
        LOADB(bBv, k0 + 1);
        LOADA(aR, k0);     MFMAS(aR, bA);
        LOADB(bA, k0 + 2);
        LOADA(aR, k0 + 1); MFMAS(aR, bBv);
        LOADA(aR, k0 + 2); MFMAS(aR, bA);
        if (j < 7) LOADB(bA, k0 + 3);   // covered by next FFT chunk
      }
    }

    // ---- GroupNorm stats (deterministic in-block reduction) ----
    float s = 0.f, ss = 0.f;
#pragma unroll
    for (int mf = 0; mf < 4; ++mf)
#pragma unroll
      for (int nf = 0; nf < 4; ++nf)
#pragma unroll
        for (int r = 0; r < 4; ++r) {
          float t = acc[mf][nf][r];
          s += t;
          ss += t * t;
        }
#pragma unroll
    for (int off = 32; off > 0; off >>= 1) {
      s  += __shfl_xor(s, off, 64);
      ss += __shfl_xor(ss, off, 64);
    }
    if (lane == 0) { redS[par][wid] = s; redQ[par][wid] = ss; }
    __syncthreads();
    float Stot = 0.f, Qtot = 0.f;
#pragma unroll
    for (int i = 0; i < 12; ++i) { Stot += redS[par][i]; Qtot += redQ[par][i]; }
    constexpr float invN = 1.0f / 49152.0f;
    const float mean = Stot * invN;
    const float inv  = rsqrtf(fmaxf(Qtot * invN - mean * mean, 0.f) + 1e-5f);

    // ---- GN + GELU, write out[b][hw][o]; stores drain under next b's FFT ----
    float* outb = out + (size_t)b * NEL;
#pragma unroll
    for (int nf = 0; nf < 4; ++nf) {
      const int o = wid * 64 + nf * 16 + l15;
      const float gw = gnw[o], gb_ = gnb[o];
#pragma unroll
      for (int mf = 0; mf < 4; ++mf)
#pragma unroll
        for (int r = 0; r < 4; ++r) {
          const int hw = mf * 16 + g * 4 + r;
          float t = (acc[mf][nf][r] - mean) * inv;
          t = t * gw + gb_;
          outb[(size_t)hw * O_DIM + o] = gelu_fast(t);
        }
    }
    par ^= 1;
  }
#undef LOADA
#undef LOADB
#undef MFMAS
}

extern "C" void kernel_launch(void* const* d_in, const int* in_sizes, int n_in,
                              void* d_out, int out_size, void* d_ws, size_t ws_size,
                              hipStream_t stream) {
  const float* x   = (const float*)d_in[0];
  const float* wre = (const float*)d_in[1];
  const float* wim = (const float*)d_in[2];
  const float* pw  = (const float*)d_in[3];
  const float* gnw = (const float*)d_in[4];
  const float* gnb = (const float*)d_in[5];
  float* out = (float*)d_out;

  const int B = in_sizes[0] / NEL;  // 1024

  unsigned short* projB = (unsigned short*)d_ws;
  float* wT0 = (float*)((char*)d_ws + (2u << 20));
  float* wT1 = (float*)((char*)d_ws + (2u << 20) + (256u << 10));

  k_convert_proj<<<288, 256, 0, stream>>>(pw, projB);
  k_prep_w<<<120, 256, 0, stream>>>(wre, wim, wT0, wT1);
  k_fused<<<256, 768, 0, stream>>>(x, wT0, wT1, projB, gnw, gnb, out, B);
}

// Round 9
// 176.162 us; speedup vs baseline: 3.0390x; 1.9267x over previous
//
#include <hip/hip_runtime.h>
#include <cstddef>

typedef __attribute__((ext_vector_type(4))) float  float4v;
typedef __attribute__((ext_vector_type(8))) short  short8v;
typedef __attribute__((ext_vector_type(8))) unsigned short ushort8v;
typedef __attribute__((ext_vector_type(8))) __bf16 bf16x8;
typedef __attribute__((ext_vector_type(4))) float  f32x4;

static constexpr int C_DIM = 768;
static constexpr int O_DIM = 768;
static constexpr int NEL   = 49152;  // 768*64

__device__ __forceinline__ unsigned short f2bf(float f) {
  __bf16 h = (__bf16)f;
  return __builtin_bit_cast(unsigned short, h);
}

// forward 8-pt real FFT (unnormalized), packed output [Re0,Re1,Re2,Re3,Re4,Im3,Im2,Im1]
__device__ __forceinline__ void rfft8p(float& x0, float& x1, float& x2, float& x3,
                                       float& x4, float& x5, float& x6, float& x7) {
  const float Cc = 0.70710678118654752f;
  float b0 = x0 + x4, b1 = x1 + x5, b2 = x2 + x6, b3 = x3 + x7;
  float d0 = x0 - x4, d1 = x1 - x5, d2 = x2 - x6, d3 = x3 - x7;
  float e0 = b0 + b2, e1 = b1 + b3, f0 = b0 - b2, f1 = b1 - b3;
  float t1 = Cc * (d1 - d3), t2 = Cc * (d1 + d3);
  x0 = e0 + e1; x4 = e0 - e1;
  x2 = f0;      x6 = -f1;
  x1 = d0 + t1; x7 = -(t2 + d2);
  x3 = d0 - t1; x5 = d2 - t2;
}

__device__ __forceinline__ void irfft8p(float& x0, float& x1, float& x2, float& x3,
                                        float& x4, float& x5, float& x6, float& x7) {
  const float Cc = 0.70710678118654752f;
  float R0 = x0, R1 = x1, R2 = x2, R3 = x3, R4 = x4, I3 = x5, I2 = x6, I1 = x7;
  float p = R0 + R4, q = R0 - R4;
  float u = 2.f * R2, vv = 2.f * I2;
  float g1 = R1 + R3, g2 = R1 - R3, g3 = I1 + I3, g4 = I1 - I3;
  float E1 = p + u, E2 = p - u;
  float B1 = 2.f * g1, B2 = 2.f * g4;
  float A1 = 2.f * Cc * (g2 - g3), A2c_ = 2.f * Cc * (g2 + g3);
  x0 = E1 + B1;  x4 = E1 - B1;
  x2 = E2 - B2;  x6 = E2 + B2;
  x1 = q + A1 - vv;  x5 = q - A1 - vv;
  x3 = q - A2c_ + vv;  x7 = q + A2c_ + vv;
}

template<bool INV>
__device__ __forceinline__ void cfft8(
    float& r0, float& r1, float& r2, float& r3, float& r4, float& r5, float& r6, float& r7,
    float& i0, float& i1, float& i2, float& i3, float& i4, float& i5, float& i6, float& i7) {
  const float Cc = 0.70710678118654752f;
  float s0r = r0 + r4, s0i = i0 + i4, s1r = r2 + r6, s1i = i2 + i6;
  float t0r = r0 - r4, t0i = i0 - i4, t1r = r2 - r6, t1i = i2 - i6;
  float E0r = s0r + s1r, E0i = s0i + s1i;
  float E2r = s0r - s1r, E2i = s0i - s1i;
  float E1r, E1i, E3r, E3i;
  if (!INV) { E1r = t0r + t1i; E1i = t0i - t1r; E3r = t0r - t1i; E3i = t0i + t1r; }
  else      { E1r = t0r - t1i; E1i = t0i + t1r; E3r = t0r + t1i; E3i = t0i - t1r; }
  float u0r = r1 + r5, u0i = i1 + i5, u1r = r3 + r7, u1i = i3 + i7;
  float p0r = r1 - r5, p0i = i1 - i5, p1r = r3 - r7, p1i = i3 - i7;
  float O0r = u0r + u1r, O0i = u0i + u1i;
  float O2r = u0r - u1r, O2i = u0i - u1i;
  float O1r, O1i, O3r, O3i;
  if (!INV) { O1r = p0r + p1i; O1i = p0i - p1r; O3r = p0r - p1i; O3i = p0i + p1r; }
  else      { O1r = p0r - p1i; O1i = p0i + p1r; O3r = p0r + p1i; O3i = p0i - p1r; }
  float W1r, W1i, W2r, W2i, W3r, W3i;
  if (!INV) {
    W1r = Cc * (O1r + O1i); W1i = Cc * (O1i - O1r);
    W2r = O2i;              W2i = -O2r;
    W3r = Cc * (O3i - O3r); W3i = -Cc * (O3r + O3i);
  } else {
    W1r = Cc * (O1r - O1i); W1i = Cc * (O1i + O1r);
    W2r = -O2i;             W2i = O2r;
    W3r = -Cc * (O3r + O3i); W3i = Cc * (O3r - O3i);
  }
  r0 = E0r + O0r; i0 = E0i + O0i;  r4 = E0r - O0r; i4 = E0i - O0i;
  r1 = E1r + W1r; i1 = E1i + W1i;  r5 = E1r - W1r; i5 = E1i - W1i;
  r2 = E2r + W2r; i2 = E2i + W2i;  r6 = E2r - W2r; i6 = E2i - W2i;
  r3 = E3r + W3r; i3 = E3i + W3i;  r7 = E3r - W3r; i7 = E3i - W3i;
}

// ---------------- K0: proj_w f32 -> bf16 in MFMA B-fragment layout ----------------
__global__ __launch_bounds__(256) void k_convert_proj(const float* __restrict__ p,
                                                      unsigned short* __restrict__ pb) {
  int t = blockIdx.x * 256 + threadIdx.x;
  int o = t / 96, cb = t - o * 96;
  const float* src = p + o * 768 + cb * 8;
  float4v v0 = *(const float4v*)(src);
  float4v v1 = *(const float4v*)(src + 4);
  ushort8v w;
#pragma unroll
  for (int r = 0; r < 4; ++r) { w[r] = f2bf(v0[r]); w[r + 4] = f2bf(v1[r]); }
  int ks = cb >> 2, g = cb & 3;
  int nf = o >> 4, l15 = o & 15;
  size_t off = ((size_t)(ks * 48 + nf) * 64 + g * 16 + l15) * 8;
  *(ushort8v*)(pb + off) = w;
}

// ---------------- K0b: pre-transpose + symmetrize spectral weights ----------------
__global__ __launch_bounds__(256) void k_prep_w(const float* __restrict__ wre,
                                                const float* __restrict__ wim,
                                                float* __restrict__ wT0,
                                                float* __restrict__ wT1) {
  int i = blockIdx.x * 256 + threadIdx.x;   // 40*768 = 30720
  if (i >= 40 * 768) return;
  int k = i / 768, c = i - k * 768;
  int h = k / 5, w = k - h * 5;
  const float S = 1.0f / 64.0f;
  const float* wr = wre + c * 40;
  const float* wi = wim + c * 40;
  float ar, ai;
  if (w == 0 || w == 4) {
    if (h == 0 || h == 4)      { ar = wr[k] * S; ai = 0.f; }
    else if (h <= 3)           { ar = (wr[h * 5 + w] + wr[(8 - h) * 5 + w]) * (0.5f * S);
                                 ai = (wi[h * 5 + w] - wi[(8 - h) * 5 + w]) * (0.5f * S); }
    else                       { ar = 0.f; ai = 0.f; }
  } else                       { ar = wr[k] * S; ai = wi[k] * S; }
  wT0[i] = ar; wT1[i] = ai;
}

// ---------------- fused kernel: half-K A-tile (48 KB LDS -> 2 blocks/CU) ----------
__device__ __forceinline__ float gelu_fast(float x) {
  float p = x * x;
  float q = fmaf(p, -0.1029434f, -2.3022082f);
  float e = exp2f(x * q);
  return x * __builtin_amdgcn_rcpf(1.0f + e);
}

// one channel's 8x8 spectral filter; writes A2[hw][lc] (384-ch tile, swizzled bf16)
__device__ __forceinline__ void fft_tile(const float* __restrict__ xb, int c, int lc,
                                         const float* __restrict__ wT0,
                                         const float* __restrict__ wT1,
                                         unsigned short* A2) {
  float v[8][8];
#pragma unroll
  for (int m = 0; m < 8; ++m)
#pragma unroll
    for (int n = 0; n < 8; ++n) v[m][n] = xb[(m * 8 + n) * C_DIM + c];

#define ROWV(m) v[m][0], v[m][1], v[m][2], v[m][3], v[m][4], v[m][5], v[m][6], v[m][7]
#define COLV(w) v[0][w], v[1][w], v[2][w], v[3][w], v[4][w], v[5][w], v[6][w], v[7][w]
#pragma unroll
  for (int m = 0; m < 8; ++m) rfft8p(ROWV(m));
  rfft8p(COLV(0));
  rfft8p(COLV(4));
  cfft8<false>(COLV(1), COLV(7));
  cfft8<false>(COLV(2), COLV(6));
  cfft8<false>(COLV(3), COLV(5));

#define LR(k) wT0[(k) * 768 + c]
#define LI(k) wT1[(k) * 768 + c]
#pragma unroll
  for (int w = 0; w <= 4; w += 4) {
    v[0][w] *= LR(w);
    v[4][w] *= LR(20 + w);
#pragma unroll
    for (int h = 1; h <= 3; ++h) {
      float ar = LR(h * 5 + w), ai = LI(h * 5 + w);
      float re = v[h][w], im = v[8 - h][w];
      v[h][w]     = re * ar - im * ai;
      v[8 - h][w] = re * ai + im * ar;
    }
  }
#pragma unroll
  for (int w = 1; w <= 3; ++w) {
#pragma unroll
    for (int h = 0; h < 8; ++h) {
      float ar = LR(h * 5 + w), ai = LI(h * 5 + w);
      float re = v[h][w], im = v[h][8 - w];
      v[h][w]     = re * ar - im * ai;
      v[h][8 - w] = re * ai + im * ar;
    }
  }
#undef LR
#undef LI

  irfft8p(COLV(0));
  irfft8p(COLV(4));
  cfft8<true>(COLV(1), COLV(7));
  cfft8<true>(COLV(2), COLV(6));
  cfft8<true>(COLV(3), COLV(5));
#pragma unroll
  for (int m = 0; m < 8; ++m) irfft8p(ROWV(m));
#undef ROWV
#undef COLV

  // A2[hw][lc] bf16, row stride 768 B, byte XOR-swizzle ((hw&7)<<4)
  char* base = (char*)A2;
#pragma unroll
  for (int m = 0; m < 8; ++m)
#pragma unroll
    for (int n = 0; n < 8; ++n) {
      const int hw = m * 8 + n;
      int off = (hw * 768 + lc * 2) ^ ((hw & 7) << 4);
      *(unsigned short*)(base + off) = f2bf(v[m][n]);
    }
}

__global__ __launch_bounds__(512, 2) void k_fused(const float* __restrict__ x,
                                                  const float* __restrict__ wT0,
                                                  const float* __restrict__ wT1,
                                                  const unsigned short* __restrict__ projB,
                                                  const float* __restrict__ gnw,
                                                  const float* __restrict__ gnb,
                                                  float* __restrict__ out) {
  __shared__ __align__(16) unsigned short A2[64 * 384];  // 48 KB -> 2 blocks/CU
  __shared__ float redS[8], redQ[8];

  const int b    = blockIdx.x;
  const int tid  = threadIdx.x;
  const int wid  = tid >> 6;        // 0..7, wave owns o in [wid*96, wid*96+96)
  const int lane = tid & 63;
  const int g    = lane >> 4;
  const int l15  = lane & 15;

  const unsigned short* Bb = projB + ((size_t)(wid * 6) * 64 + lane) * 8;
  const char* A2c = (const char*)A2;
  const int swz = (l15 & 7) << 4;
  const float* xb = x + (size_t)b * NEL;

#define LOADB(BF, KS)                                                        \
  do {                                                                       \
    _Pragma("unroll") for (int nf = 0; nf < 6; ++nf)                         \
        BF[nf] = *(const short8v*)&Bb[(KS) * 24576 + nf * 512];              \
  } while (0)

#define LOADA(AF, KS)                                                        \
  do {                                                                       \
    _Pragma("unroll") for (int mf = 0; mf < 4; ++mf)                         \
        AF[mf] = *(const short8v*)(A2c +                                     \
            (((mf * 16 + l15) * 768 + (KS) * 64 + g * 16) ^ swz));           \
  } while (0)

#define MFMAS(AF, BF)                                                        \
  do {                                                                       \
    _Pragma("unroll") for (int mf = 0; mf < 4; ++mf)                         \
        _Pragma("unroll") for (int nf = 0; nf < 6; ++nf)                     \
            acc[mf][nf] = __builtin_amdgcn_mfma_f32_16x16x32_bf16(           \
                __builtin_bit_cast(bf16x8, AF[mf]), __builtin_bit_cast(bf16x8, BF[nf]),\
                acc[mf][nf], 0, 0, 0);                                       \
  } while (0)

  short8v b0[6], b1[6], b2[6], aR[4];

  // B ks0 prefetch; L2 latency hides under FFT half 0
  LOADB(b0, 0);

  // ---- FFT half 0: channels 0..383 ----
  if (tid < 384) fft_tile(xb, tid, tid, wT0, wT1, A2);
  __syncthreads();

  f32x4 acc[4][6];
#pragma unroll
  for (int mf = 0; mf < 4; ++mf)
#pragma unroll
    for (int nf = 0; nf < 6; ++nf) acc[mf][nf] = f32x4{0.f, 0.f, 0.f, 0.f};

  // ---- GEMM half 0: global ks 0..11 (A local 0..11) ----
  LOADB(b1, 1);
#pragma unroll 1
  for (int ks = 0; ks < 9; ks += 3) {
    LOADB(b2, ks + 2); LOADA(aR, ks);     MFMAS(aR, b0);
    LOADB(b0, ks + 3); LOADA(aR, ks + 1); MFMAS(aR, b1);
    LOADB(b1, ks + 4); LOADA(aR, ks + 2); MFMAS(aR, b2);
  }
  LOADB(b2, 11); LOADA(aR, 9);  MFMAS(aR, b0);
  LOADB(b0, 12); LOADA(aR, 10); MFMAS(aR, b1);   // b0 <- ks12, survives barrier
  LOADA(aR, 11); MFMAS(aR, b2);
  __syncthreads();                                // A2 reuse fence

  // ---- FFT half 1: channels 384..767 ----
  if (tid < 384) fft_tile(xb, 384 + tid, tid, wT0, wT1, A2);
  __syncthreads();

  // ---- GEMM half 1: global ks 12..23 (A local 0..11) ----
  LOADB(b1, 13);
#pragma unroll 1
  for (int ks = 0; ks < 9; ks += 3) {
    LOADB(b2, ks + 14); LOADA(aR, ks);     MFMAS(aR, b0);
    LOADB(b0, ks + 15); LOADA(aR, ks + 1); MFMAS(aR, b1);
    LOADB(b1, ks + 16); LOADA(aR, ks + 2); MFMAS(aR, b2);
  }
  LOADB(b2, 23); LOADA(aR, 9);  MFMAS(aR, b0);
  LOADA(aR, 10); MFMAS(aR, b1);
  LOADA(aR, 11); MFMAS(aR, b2);

  // ---- GroupNorm stats (deterministic in-block reduction) ----
  float s = 0.f, ss = 0.f;
#pragma unroll
  for (int mf = 0; mf < 4; ++mf)
#pragma unroll
    for (int nf = 0; nf < 6; ++nf)
#pragma unroll
      for (int r = 0; r < 4; ++r) {
        float t = acc[mf][nf][r];
        s += t;
        ss += t * t;
      }
#pragma unroll
  for (int off = 32; off > 0; off >>= 1) {
    s  += __shfl_xor(s, off, 64);
    ss += __shfl_xor(ss, off, 64);
  }
  if (lane == 0) { redS[wid] = s; redQ[wid] = ss; }
  __syncthreads();
  float Stot = 0.f, Qtot = 0.f;
#pragma unroll
  for (int i = 0; i < 8; ++i) { Stot += redS[i]; Qtot += redQ[i]; }
  constexpr float invN = 1.0f / 49152.0f;
  const float mean = Stot * invN;
  const float inv  = rsqrtf(fmaxf(Qtot * invN - mean * mean, 0.f) + 1e-5f);

  // ---- GN + GELU, write out[b][hw][o] ----
  float* outb = out + (size_t)b * NEL;
#pragma unroll
  for (int nf = 0; nf < 6; ++nf) {
    const int o = wid * 96 + nf * 16 + l15;
    const float gw = gnw[o], gb_ = gnb[o];
#pragma unroll
    for (int mf = 0; mf < 4; ++mf)
#pragma unroll
      for (int r = 0; r < 4; ++r) {
        const int hw = mf * 16 + g * 4 + r;
        float t = (acc[mf][nf][r] - mean) * inv;
        t = t * gw + gb_;
        outb[(size_t)hw * O_DIM + o] = gelu_fast(t);
      }
  }
#undef LOADA
#undef LOADB
#undef MFMAS
}

extern "C" void kernel_launch(void* const* d_in, const int* in_sizes, int n_in,
                              void* d_out, int out_size, void* d_ws, size_t ws_size,
                              hipStream_t stream) {
  const float* x   = (const float*)d_in[0];
  const float* wre = (const float*)d_in[1];
  const float* wim = (const float*)d_in[2];
  const float* pw  = (const float*)d_in[3];
  const float* gnw = (const float*)d_in[4];
  const float* gnb = (const float*)d_in[5];
  float* out = (float*)d_out;

  const int B = in_sizes[0] / NEL;  // 1024

  unsigned short* projB = (unsigned short*)d_ws;
  float* wT0 = (float*)((char*)d_ws + (2u << 20));
  float* wT1 = (float*)((char*)d_ws + (2u << 20) + (256u << 10));

  k_convert_proj<<<288, 256, 0, stream>>>(pw, projB);
  k_prep_w<<<120, 256, 0, stream>>>(wre, wim, wT0, wT1);
  k_fused<<<B, 512, 0, stream>>>(x, wT0, wT1, projB, gnw, gnb, out);
}